// Round 1
// baseline (591.377 us; speedup 1.0000x reference)
//
#include <hip/hip_runtime.h>
#include <cstddef>

#define NPTS 500000
#define DF 64
#define NC 10000
#define BN_EPS 1e-5f

#define TPB 256
#define PTILE 64
#define NTILES ((NPTS + PTILE - 1) / PTILE)  // 7813
#define NBLK 768                             // 3 blocks/CU x 256 CU (LDS-bound)

// ---- order-preserving float<->uint encoding (for atomic max on floats) ----
__device__ __forceinline__ unsigned f2o(float f) {
  unsigned u = __float_as_uint(f);
  return (u & 0x80000000u) ? ~u : (u | 0x80000000u);
}
__device__ __forceinline__ float o2f(unsigned u) {
  return __uint_as_float((u & 0x80000000u) ? (u ^ 0x80000000u) : ~u);
}

// async global->LDS, 16B per lane. LDS dest is wave-uniform base + lane*16.
__device__ __forceinline__ void gload16(const float* g, float* l) {
  __builtin_amdgcn_global_load_lds(
      (const __attribute__((address_space(1))) void*)g,
      (__attribute__((address_space(3))) void*)l, 16, 0, 0);
}

// Stage one 64-point x tile (16 KB) into a linear LDS buffer via 4
// global_load_lds_dwordx4 per wave. Source is PRE-SWIZZLED: LDS 16B-slot
// (p, jb) receives x[p][(jb ^ (p>>2))*4 ..], so the compute-side read
// xv(p, j4) at slot (p, j4 ^ (p>>2)) is bank-conflict-free (16 banks/instr)
// while the LDS destination stays linear as global_load_lds requires.
__device__ __forceinline__ void stage_tile(float* xsbuf, const float* x,
                                           int pbase, int wave, int lane) {
#pragma unroll
  for (int i = 0; i < 4; ++i) {
    const int chunk = wave * 4 + i;       // 0..15, wave-uniform
    const int slot = chunk * 64 + lane;   // 16B slot id 0..1023
    const int p = slot >> 4;              // local point 0..63
    const int jb = slot & 15;             // 16B column block
    int gp = pbase + p;
    if (gp >= NPTS) gp = NPTS - 1;        // tail/overshoot: safe garbage row
    const int jsrc = jb ^ (p >> 2);
    gload16(x + (size_t)gp * DF + jsrc * 4, xsbuf + chunk * 256);
  }
}

// ws layout (float/uint units):
// 0        : q_u     [NC*DF]   sortable-uint segment max of Q projections
// 640000   : mmax_u  [NC]      sortable-uint segment max of M
// 650000   : denom   [NC]      segment sum of exp
// 660000   : sums    [2*DF]    [sum h | sum h^2]
// 660128   : scale   [DF]
// 660192   : shift   [DF]
// 660256   : Mv      [NPTS]

// MODE 0: Q proj -> segment max into q_u (read-filtered atomics)
// MODE 1: K proj -> M = dot(q[c],k), store Mv, atomicMax mmax_u
// MODE 2: V proj -> h = attn*v, accumulate BN stats (no h store)
// MODE 3: V proj -> h, normalize + relu, write out
template <int MODE>
__launch_bounds__(TPB, 3)
__global__ void proj_kernel(
    const float* __restrict__ x, const int* __restrict__ cluster,
    const float* __restrict__ W, const float* __restrict__ bias,
    unsigned* __restrict__ q_u, unsigned* __restrict__ mmax_u,
    const float* __restrict__ denom, float* __restrict__ Mv,
    float* __restrict__ sums, const float* __restrict__ scale,
    const float* __restrict__ shift, float* __restrict__ out) {
  __shared__ float Wt[DF * DF];         // Wt[j][f] = W[f][j], stride 64
  __shared__ float xs[2][PTILE * DF];   // double-buffered x tiles, linear

  const int tid = threadIdx.x;
  const int lane = tid & 63;
  const int wave = tid >> 6;
  const int fg = tid & 15;   // feature group
  const int pg = tid >> 4;   // point group (0..15)
  const int f0 = fg * 4;

  // ---- stage W transposed (once per block) ----
  {
    const int f = tid & 63;
    const int jb = (tid >> 6) * 16;
#pragma unroll
    for (int i = 0; i < 4; ++i) {
      float4 wr = *(const float4*)(W + f * DF + jb + i * 4);
      Wt[(jb + i * 4 + 0) * DF + f] = wr.x;
      Wt[(jb + i * 4 + 1) * DF + f] = wr.y;
      Wt[(jb + i * 4 + 2) * DF + f] = wr.z;
      Wt[(jb + i * 4 + 3) * DF + f] = wr.w;
    }
  }
  const float4 bv4 = *(const float4*)(bias + f0);
  float4 sc4 = make_float4(0.f, 0.f, 0.f, 0.f);
  float4 sh4 = make_float4(0.f, 0.f, 0.f, 0.f);
  if (MODE == 3) {
    sc4 = *(const float4*)(scale + f0);
    sh4 = *(const float4*)(shift + f0);
  }
  float4 s1 = make_float4(0.f, 0.f, 0.f, 0.f);
  float4 s2 = make_float4(0.f, 0.f, 0.f, 0.f);

  // ---- prologue: issue tile t0 into buf0, drain, barrier (covers Wt) ----
  int t = blockIdx.x;
  stage_tile(xs[0], x, t * PTILE, wave, lane);
  asm volatile("s_waitcnt vmcnt(0) lgkmcnt(0)" ::: "memory");
  __builtin_amdgcn_s_barrier();
  asm volatile("" ::: "memory");

  int cur = 0;
  for (; t < NTILES; t += NBLK) {
    const int pbase = t * PTILE;
    // ---- prefetch tile t+NBLK into the other buffer (in flight under GEMM)
    stage_tile(xs[cur ^ 1], x, (t + NBLK) * PTILE, wave, lane);
    // ---- cluster ids for this thread's 4 points (registers, no LDS)
    int4 c4;
    {
      const int cb = pbase + pg * 4;
      if (cb + 3 < NPTS) {
        c4 = *(const int4*)(cluster + cb);
      } else {
        c4.x = cluster[cb + 0 < NPTS ? cb + 0 : NPTS - 1];
        c4.y = cluster[cb + 1 < NPTS ? cb + 1 : NPTS - 1];
        c4.z = cluster[cb + 2 < NPTS ? cb + 2 : NPTS - 1];
        c4.w = cluster[cb + 3 < NPTS ? cb + 3 : NPTS - 1];
      }
    }
    asm volatile("" ::: "memory");  // keep prefetch issue ahead of compute

    // ---- register-blocked GEMM: acc[pp] = x[p] . W[f0..f0+3] + b ----
    const float* xrow = &xs[cur][(pg * 4) * DF];
    float4 acc[4];
#pragma unroll
    for (int pp = 0; pp < 4; ++pp) acc[pp] = bv4;
#pragma unroll 4
    for (int j4 = 0; j4 < 16; ++j4) {
      float4 wv[4];  // wv[e][comp] = W[f0+comp][j4*4+e]
#pragma unroll
      for (int e = 0; e < 4; ++e)
        wv[e] = *(const float4*)(Wt + (j4 * 4 + e) * DF + f0);
      const int xoff = (j4 ^ pg) * 4;  // matches stage-side source swizzle
#pragma unroll
      for (int pp = 0; pp < 4; ++pp) {
        float4 xv = *(const float4*)(xrow + pp * DF + xoff);
        acc[pp].x = fmaf(xv.x, wv[0].x, acc[pp].x);
        acc[pp].y = fmaf(xv.x, wv[0].y, acc[pp].y);
        acc[pp].z = fmaf(xv.x, wv[0].z, acc[pp].z);
        acc[pp].w = fmaf(xv.x, wv[0].w, acc[pp].w);
        acc[pp].x = fmaf(xv.y, wv[1].x, acc[pp].x);
        acc[pp].y = fmaf(xv.y, wv[1].y, acc[pp].y);
        acc[pp].z = fmaf(xv.y, wv[1].z, acc[pp].z);
        acc[pp].w = fmaf(xv.y, wv[1].w, acc[pp].w);
        acc[pp].x = fmaf(xv.z, wv[2].x, acc[pp].x);
        acc[pp].y = fmaf(xv.z, wv[2].y, acc[pp].y);
        acc[pp].z = fmaf(xv.z, wv[2].z, acc[pp].z);
        acc[pp].w = fmaf(xv.z, wv[2].w, acc[pp].w);
        acc[pp].x = fmaf(xv.w, wv[3].x, acc[pp].x);
        acc[pp].y = fmaf(xv.w, wv[3].y, acc[pp].y);
        acc[pp].z = fmaf(xv.w, wv[3].z, acc[pp].z);
        acc[pp].w = fmaf(xv.w, wv[3].w, acc[pp].w);
      }
    }

    // ---- mode-specific epilogue ----
#pragma unroll
    for (int pp = 0; pp < 4; ++pp) {
      const int p = pbase + pg * 4 + pp;
      const int cc = (pp == 0) ? c4.x : (pp == 1) ? c4.y : (pp == 2) ? c4.z
                                                                     : c4.w;
      if (MODE == 0) {
        if (p < NPTS) {
          unsigned* dst = q_u + (size_t)cc * DF + f0;
          // q_u is monotonically non-decreasing, so a (possibly stale)
          // plain read can only under-report: skipping when new <= cached
          // is race-safe and kills ~90% of the atomics.
          const uint4 curq = *(const uint4*)dst;
          const unsigned ex = f2o(acc[pp].x);
          const unsigned ey = f2o(acc[pp].y);
          const unsigned ez = f2o(acc[pp].z);
          const unsigned ew = f2o(acc[pp].w);
          if (ex > curq.x) atomicMax(dst + 0, ex);
          if (ey > curq.y) atomicMax(dst + 1, ey);
          if (ez > curq.z) atomicMax(dst + 2, ez);
          if (ew > curq.w) atomicMax(dst + 3, ew);
        }
      } else if (MODE == 1) {
        float partial = 0.f;
        if (p < NPTS) {
          const uint4 qu = *(const uint4*)(q_u + (size_t)cc * DF + f0);
          partial = o2f(qu.x) * acc[pp].x + o2f(qu.y) * acc[pp].y +
                    o2f(qu.z) * acc[pp].z + o2f(qu.w) * acc[pp].w;
        }
        // reduce across the 16 lanes sharing this point (fg bits = lane&15)
        partial += __shfl_xor(partial, 1, 64);
        partial += __shfl_xor(partial, 2, 64);
        partial += __shfl_xor(partial, 4, 64);
        partial += __shfl_xor(partial, 8, 64);
        if (fg == 0 && p < NPTS) {
          Mv[p] = partial;
          const unsigned e = f2o(partial);
          unsigned* mm = mmax_u + cc;
          if (e > *mm) atomicMax(mm, e);
        }
      } else {
        if (p < NPTS) {
          const float attn = __expf(Mv[p] - o2f(mmax_u[cc])) / denom[cc];
          float4 h;
          h.x = attn * acc[pp].x;
          h.y = attn * acc[pp].y;
          h.z = attn * acc[pp].z;
          h.w = attn * acc[pp].w;
          if (MODE == 2) {
            s1.x += h.x; s1.y += h.y; s1.z += h.z; s1.w += h.w;
            s2.x += h.x * h.x; s2.y += h.y * h.y;
            s2.z += h.z * h.z; s2.w += h.w * h.w;
          } else {
            float4 r;
            r.x = fmaxf(fmaf(h.x, sc4.x, sh4.x), 0.f);
            r.y = fmaxf(fmaf(h.y, sc4.y, sh4.y), 0.f);
            r.z = fmaxf(fmaf(h.z, sc4.z, sh4.z), 0.f);
            r.w = fmaxf(fmaf(h.w, sc4.w, sh4.w), 0.f);
            *(float4*)(out + (size_t)p * DF + f0) = r;
          }
        }
      }
    }

    // ---- pipeline turn: drain prefetch (landed during GEMM), one barrier
    asm volatile("s_waitcnt vmcnt(0)" ::: "memory");
    __builtin_amdgcn_s_barrier();
    asm volatile("" ::: "memory");
    cur ^= 1;
  }

  if constexpr (MODE == 2) {
    // block-reduce BN partial sums; alias xs as scratch (done with tiles)
    __syncthreads();
    float* red = &xs[0][0];  // red1 = [0..1023], red2 = [1024..2047]
    *(float4*)(red + pg * DF + f0) = s1;
    *(float4*)(red + 1024 + pg * DF + f0) = s2;
    __syncthreads();
    if (tid < DF) {
      float a = 0.f, b = 0.f;
#pragma unroll
      for (int g = 0; g < 16; ++g) {
        a += red[g * DF + tid];
        b += red[1024 + g * DF + tid];
      }
      atomicAdd(sums + tid, a);
      atomicAdd(sums + DF + tid, b);
    }
  }
}

__global__ void denom_kernel(const float* __restrict__ Mv,
                             const int* __restrict__ cluster,
                             const unsigned* __restrict__ mmax_u,
                             float* __restrict__ denom) {
  int i = blockIdx.x * blockDim.x + threadIdx.x;
  if (i < NPTS) {
    int c = cluster[i];
    atomicAdd(denom + c, __expf(Mv[i] - o2f(mmax_u[c])));
  }
}

__global__ void finalize_kernel(const float* __restrict__ sums,
                                const float* __restrict__ gamma,
                                const float* __restrict__ beta,
                                float* __restrict__ scale,
                                float* __restrict__ shift) {
  int d = threadIdx.x;
  float mean = sums[d] * (1.0f / NPTS);
  float var = sums[DF + d] * (1.0f / NPTS) - mean * mean;
  float s = gamma[d] * rsqrtf(var + BN_EPS);
  scale[d] = s;
  shift[d] = fmaf(-mean, s, beta[d]);
}

extern "C" void kernel_launch(void* const* d_in, const int* in_sizes, int n_in,
                              void* d_out, int out_size, void* d_ws,
                              size_t ws_size, hipStream_t stream) {
  const float* x = (const float*)d_in[1];
  const int* cluster = (const int*)d_in[2];
  const float* Wv = (const float*)d_in[3];
  const float* bv = (const float*)d_in[4];
  const float* Wk = (const float*)d_in[5];
  const float* bk = (const float*)d_in[6];
  const float* Wq = (const float*)d_in[7];
  const float* bq = (const float*)d_in[8];
  const float* gamma = (const float*)d_in[9];
  const float* beta = (const float*)d_in[10];
  float* out = (float*)d_out;

  float* ws = (float*)d_ws;
  unsigned* q_u = (unsigned*)ws;
  unsigned* mmax_u = (unsigned*)(ws + 640000);
  float* denom = ws + 650000;
  float* sums = ws + 660000;
  float* scale = ws + 660128;
  float* shift = ws + 660192;
  float* Mv = ws + 660256;

  // zero q_u / mmax_u / denom / sums (0u == sortable "-inf" sentinel)
  hipMemsetAsync(d_ws, 0, 660256 * sizeof(float), stream);

  proj_kernel<0><<<NBLK, TPB, 0, stream>>>(x, cluster, Wq, bq, q_u, mmax_u,
                                           denom, Mv, sums, scale, shift, out);
  proj_kernel<1><<<NBLK, TPB, 0, stream>>>(x, cluster, Wk, bk, q_u, mmax_u,
                                           denom, Mv, sums, scale, shift, out);
  denom_kernel<<<(NPTS + 255) / 256, 256, 0, stream>>>(Mv, cluster, mmax_u,
                                                       denom);
  proj_kernel<2><<<NBLK, TPB, 0, stream>>>(x, cluster, Wv, bv, q_u, mmax_u,
                                           denom, Mv, sums, scale, shift, out);
  finalize_kernel<<<1, 64, 0, stream>>>(sums, gamma, beta, scale, shift);
  proj_kernel<3><<<NBLK, TPB, 0, stream>>>(x, cluster, Wv, bv, q_u, mmax_u,
                                           denom, Mv, sums, scale, shift, out);
}